// Round 14
// baseline (1090.881 us; speedup 1.0000x reference)
//
#include <hip/hip_runtime.h>
#include <cstdint>
#include <cstddef>

#define B_ 2048
#define N_ 49
#define H_ 1024
#define A_ 512
#define M_ (B_*N_)   // 100352 = 392*256

typedef __attribute__((ext_vector_type(8))) short short8;
typedef __attribute__((ext_vector_type(8))) unsigned short ushort8;
typedef __attribute__((ext_vector_type(4))) float f32x4;
typedef unsigned int u32;

__device__ inline unsigned short f2bf(float f){
  union { float f; unsigned u; } v; v.f = f;
  unsigned r = v.u + 0x7FFFu + ((v.u >> 16) & 1u);   // RNE
  return (unsigned short)(r >> 16);
}
__device__ inline float bf2f(unsigned short h){
  union { u32 u; float f; } v; v.u = ((u32)h) << 16; return v.f;
}
__device__ inline float fast_tanh(float x){
  float e = __expf(2.0f*x);
  return 1.0f - 2.0f/(e + 1.0f);
}
__device__ inline void gl16(const void* g, void* l){
  __builtin_amdgcn_global_load_lds((const __attribute__((address_space(1))) u32*)g,
                                   (__attribute__((address_space(3))) u32*)l, 16, 0, 0);
}

// ---------- W (H x A fp32, row-major) -> Wt (A x H bf16) ----------
__global__ __launch_bounds__(256) void k_transpose(
    const float* __restrict__ Wh, const float* __restrict__ Wimg,
    unsigned short* __restrict__ WtH, unsigned short* __restrict__ WtImg){
  const float* src = blockIdx.y ? Wimg : Wh;
  unsigned short* dst = blockIdx.y ? WtImg : WtH;
  int tk = (blockIdx.x & 31) * 32;
  int ta = (blockIdx.x >> 5) * 32;
  __shared__ unsigned short tile[32][33];
  int t = threadIdx.x;
  int r = t >> 3, c4 = t & 7;
  float4 vv = *(const float4*)(src + (size_t)(tk + r)*A_ + ta + c4*4);
  tile[c4*4+0][r] = f2bf(vv.x);
  tile[c4*4+1][r] = f2bf(vv.y);
  tile[c4*4+2][r] = f2bf(vv.z);
  tile[c4*4+3][r] = f2bf(vv.w);
  __syncthreads();
  ushort4 o;
  o.x = tile[r][c4*4+0]; o.y = tile[r][c4*4+1];
  o.z = tile[r][c4*4+2]; o.w = tile[r][c4*4+3];
  *(ushort4*)(dst + (size_t)(ta + r)*H_ + tk + c4*4) = o;
}

// ---------- img fp32 -> bf16 ----------
__global__ __launch_bounds__(256) void k_convert(
    const float* __restrict__ src, unsigned short* __restrict__ dst, size_t n8){
  size_t i = (size_t)blockIdx.x*256 + threadIdx.x;
  size_t stride = (size_t)gridDim.x*256;
  const float4* s4 = (const float4*)src;
  ushort8* d8 = (ushort8*)dst;
  for (; i < n8; i += stride){
    float4 a = s4[2*i], b = s4[2*i+1];
    ushort8 o;
    o[0]=f2bf(a.x); o[1]=f2bf(a.y); o[2]=f2bf(a.z); o[3]=f2bf(a.w);
    o[4]=f2bf(b.x); o[5]=f2bf(b.y); o[6]=f2bf(b.z); o[7]=f2bf(b.w);
    d8[i] = o;
  }
}

// ================= fallback GEMM core (round-1) =================
#define BK 64
#define LDK 72

__device__ inline void gemm_tile(const float* __restrict__ Asrc,
                                 const unsigned short* __restrict__ Wt,
                                 int m0, int a0, f32x4 acc[4][4],
                                 unsigned short (*sA)[LDK], unsigned short (*sB)[LDK]){
  const int t = threadIdx.x;
  const int l = t & 63, w = t >> 6;
  const int wr = w >> 1, wc = w & 1;
  const int g = l >> 4, c = l & 15;
  #pragma unroll
  for (int m=0;m<4;m++)
    #pragma unroll
    for (int n=0;n<4;n++)
      acc[m][n] = f32x4{0.f,0.f,0.f,0.f};

  for (int k0 = 0; k0 < H_; k0 += BK){
    #pragma unroll
    for (int i=0;i<8;i++){
      int f = i*256 + t;
      int row = f >> 4, c4 = f & 15;
      float4 vv = *(const float4*)(Asrc + (size_t)(m0+row)*H_ + k0 + c4*4);
      ushort4 h; h.x=f2bf(vv.x); h.y=f2bf(vv.y); h.z=f2bf(vv.z); h.w=f2bf(vv.w);
      *(ushort4*)&sA[row][c4*4] = h;
    }
    #pragma unroll
    for (int i=0;i<8;i++){
      int f = i*256 + t;
      int row = f >> 4, c4 = f & 15;
      *(ushort4*)&sB[row][c4*4] = *(const ushort4*)(Wt + (size_t)(a0+row)*H_ + k0 + c4*4);
    }
    __syncthreads();
    #pragma unroll
    for (int kk=0; kk<BK; kk+=32){
      short8 aF[4], bF[4];
      #pragma unroll
      for (int m=0;m<4;m++) aF[m] = *(const short8*)&sA[wr*64 + m*16 + c][kk + g*8];
      #pragma unroll
      for (int n=0;n<4;n++) bF[n] = *(const short8*)&sB[wc*64 + n*16 + c][kk + g*8];
      #pragma unroll
      for (int m=0;m<4;m++)
        #pragma unroll
        for (int n=0;n<4;n++)
          acc[m][n] = __builtin_amdgcn_mfma_f32_16x16x32_bf16(aF[m], bF[n], acc[m][n], 0, 0, 0);
    }
    __syncthreads();
  }
}

// ---------- h_proj = hidden @ W_h + b_h ----------
__global__ __launch_bounds__(256) void k_hproj(
    const float* __restrict__ hidden, const unsigned short* __restrict__ WtH,
    const float* __restrict__ b_h, float* __restrict__ hproj){
  __shared__ __align__(16) unsigned short sA[128][LDK];
  __shared__ __align__(16) unsigned short sB[128][LDK];
  f32x4 acc[4][4];
  int m0 = blockIdx.x * 128, a0 = blockIdx.y * 128;
  gemm_tile(hidden, WtH, m0, a0, acc, sA, sB);
  const int l = threadIdx.x & 63, w = threadIdx.x >> 6;
  const int wr = w >> 1, wc = w & 1, g = l >> 4, c = l & 15;
  #pragma unroll
  for (int n=0;n<4;n++){
    int col = a0 + wc*64 + n*16 + c;
    float bh = b_h[col];
    #pragma unroll
    for (int m=0;m<4;m++)
      #pragma unroll
      for (int r=0;r<4;r++){
        int rowg = m0 + wr*64 + m*16 + g*4 + r;
        hproj[(size_t)rowg*A_ + col] = acc[m][n][r] + bh;
      }
  }
}

// ============ scores GEMM: 256x256 / BK=32 / 2 blocks/CU (occupancy lever) ============
// p8-style counted-vmcnt schedule re-parameterized: 32 K-tiles, 2 phases/tile (mh 0/1,
// 16 MFMA each), 4 staging units/tile (128 rows = 8KB = 1 gl16/thread each), issues
// split B@P0 / A@P1, counted vmcnt(2) at P0 (youngest-2 = next-tile B => tile t fully
// landed) -- never 0 in-loop. LDS 64KB total (A/B x dbuf x [256][32]) -> 2 blocks/CU,
// 16 waves/CU: cross-block overlap hides barrier/vmcnt stalls (the m114 mechanism
// none of the prior 1-block/CU variants engaged). Rows are 64B -> 2-bit XOR swizzle
// byte ^= ((row&3)<<4) (pre-applied on gl16 source; same XOR on ds_read).
__global__ __launch_bounds__(512, 4) void k_scores_q(
    const unsigned short* __restrict__ Ab, const unsigned short* __restrict__ Wt,
    const float* __restrict__ hproj, const float* __restrict__ b_img,
    const float* __restrict__ cov, const float* __restrict__ Wcov,
    const float* __restrict__ v, float* __restrict__ scoresP){
  __shared__ __align__(16) char lds[65536];
  const int t = threadIdx.x;
  const int l = t & 63, w = t >> 6;       // 8 waves
  const int wr = w >> 2, wc = w & 3;      // 2 (M) x 4 (N); per-wave 128x64 out
  const int g = l >> 4, c = l & 15;
  const int cm = (c & 3) << 4;            // read-side XOR swizzle (64B rows, 4 granules)

  // bijective XCD-chunked swizzle; wg pairs (same m-panel, a0=0/256) adjacent on one XCD.
  const int nwg = (M_/256)*(A_/256);      // 784, %8==0
  int bid = blockIdx.x;
  int wg = (bid & 7)*(nwg/8) + (bid >> 3);
  const int m0 = (wg >> 1) * 256;
  const int a0 = (wg & 1) * 256;

  // staging lane geometry: wave covers 16 rows (64B each); lane l -> row l>>2,
  // granule l&3. Pre-swizzle source granule with row&3 (= (l>>2)&3).
  const int rsub = l >> 2;
  const int ksw  = ((l & 3) ^ (rsub & 3)) * 8;   // elements

  f32x4 acc[8][4] = {};

  // one 128-row unit (8KB, 1 gl16/thread). dest is wave-uniform; HW adds lane*16.
  auto unit = [&](int d, int isB, int row0, const unsigned short* src, int prow, int k0){
    gl16(src + (size_t)(prow + row0 + w*16 + rsub)*H_ + k0 + ksw,
         lds + isB*32768 + d*16384 + (row0 + w*16)*64);
  };

  // phase (mh): 8 ds_read_b128 + 16 MFMA
  auto phase_mfma = [&](int d, int mh){
    short8 aF[4], bF[4];
    #pragma unroll
    for (int i=0;i<4;i++)
      aF[i] = *(const short8*)(lds + d*16384 + (wr*128 + mh*64 + i*16 + c)*64 + ((g*16) ^ cm));
    #pragma unroll
    for (int n=0;n<4;n++)
      bF[n] = *(const short8*)(lds + 32768 + d*16384 + (wc*64 + n*16 + c)*64 + ((g*16) ^ cm));
    asm volatile("s_waitcnt lgkmcnt(0)" ::: "memory");
    __builtin_amdgcn_sched_barrier(0);
    __builtin_amdgcn_s_setprio(1);
    #pragma unroll
    for (int i=0;i<4;i++)
      #pragma unroll
      for (int n=0;n<4;n++)
        acc[mh*4+i][n] = __builtin_amdgcn_mfma_f32_16x16x32_bf16(aF[i], bF[n], acc[mh*4+i][n], 0, 0, 0);
    __builtin_amdgcn_s_setprio(0);
  };

  // prologue: tile 0 in stream order [B-lo, B-hi, A-lo, A-hi]
  unit(0, 1, 0,   Wt, a0, 0);
  unit(0, 1, 128, Wt, a0, 0);
  unit(0, 0, 0,   Ab, m0, 0);
  unit(0, 0, 128, Ab, m0, 0);

  for (int tt=0; tt<32; ++tt){
    const int cur = tt & 1;
    const int nd  = (tt + 1) & 1;
    const int nk  = (tt + 1) * 32;
    const bool pf = (tt < 31);

    // P0: mh0; prefetch B(t+1). ledger: youngest-2 = B(t+1) -> vmcnt(2) proves
    // tile t (B then A, in-order) fully landed.
    if (pf){ unit(nd, 1, 0, Wt, a0, nk); unit(nd, 1, 128, Wt, a0, nk);
             asm volatile("s_waitcnt vmcnt(2)" ::: "memory"); }
    else   { asm volatile("s_waitcnt vmcnt(0)" ::: "memory"); }
    asm volatile("s_barrier" ::: "memory");
    phase_mfma(cur, 0);
    asm volatile("s_barrier" ::: "memory");

    // P1: mh1; prefetch A(t+1) (no wait needed)
    if (pf){ unit(nd, 0, 0, Ab, m0, nk); unit(nd, 0, 128, Ab, m0, nk); }
    asm volatile("s_barrier" ::: "memory");
    phase_mfma(cur, 1);
    asm volatile("s_barrier" ::: "memory");   // reads of buf[cur] done before t+2 staging
  }

  // ---------------- epilogue: tanh + v-dot + row-reduce (round-10, unchanged) ----------------
  float* sS = (float*)lds;            // [256]
  float* sH = (float*)lds + 256;      // [nB][256], nB<=7
  const int bFirst = m0 / N_;
  const int nB = (m0 + 255)/N_ - bFirst + 1;
  if (t < 256) sS[t] = 0.f;
  for (int idx = t; idx < nB*256; idx += 512){
    int bb = idx >> 8, a = idx & 255;
    sH[bb*256 + a] = hproj[(size_t)(bFirst + bb)*A_ + a0 + a];
  }
  __syncthreads();

  float vv[4], bi[4], wcv[4];
  #pragma unroll
  for (int n=0;n<4;n++){
    int colg = a0 + wc*64 + n*16 + c;
    vv[n] = v[colg]; bi[n] = b_img[colg]; wcv[n] = Wcov[colg];
  }
  #pragma unroll
  for (int m=0;m<8;m++){
    #pragma unroll
    for (int r=0;r<4;r++){
      int rowl = wr*128 + m*16 + g*4 + r;
      int bb = (m0 + rowl) / N_ - bFirst;
      float cv = cov[m0 + rowl];
      float s = 0.f;
      #pragma unroll
      for (int n=0;n<4;n++){
        float x = acc[m][n][r] + sH[bb*256 + wc*64 + n*16 + c] + bi[n] + cv*wcv[n];
        s += fast_tanh(x) * vv[n];
      }
      s += __shfl_xor(s, 1, 16);
      s += __shfl_xor(s, 2, 16);
      s += __shfl_xor(s, 4, 16);
      s += __shfl_xor(s, 8, 16);
      if (c == 0) atomicAdd(&sS[rowl], s);
    }
  }
  __syncthreads();
  if (t < 256) scoresP[(size_t)(a0 >> 8)*M_ + m0 + t] = sS[t];
}

// ---------- softmax (2-slab scores) + context from bf16 imgb ----------
__global__ __launch_bounds__(256) void k_ctx_b(
    const unsigned short* __restrict__ imgb, const float* __restrict__ scoresP,
    float* __restrict__ outCtx, float* __restrict__ outAlpha){
  int b = blockIdx.x;
  __shared__ float sAl[N_];
  int t = threadIdx.x;
  if (t < 64){
    float s = -1e30f;
    if (t < N_){
      size_t rg = (size_t)b*N_ + t;
      s = scoresP[rg] + scoresP[(size_t)M_ + rg];
    }
    float m = s;
    #pragma unroll
    for (int off=32; off>=1; off>>=1) m = fmaxf(m, __shfl_xor(m, off));
    float e = (t < N_) ? __expf(s - m) : 0.f;
    float sum = e;
    #pragma unroll
    for (int off=32; off>=1; off>>=1) sum += __shfl_xor(sum, off);
    float al = e / sum;
    if (t < N_){ sAl[t] = al; outAlpha[(size_t)b*N_ + t] = al; }
  }
  __syncthreads();
  float4 acc = {0.f,0.f,0.f,0.f};
  #pragma unroll 7
  for (int n=0;n<N_;n++){
    float al = sAl[n];
    ushort4 x = *(const ushort4*)(imgb + ((size_t)b*N_ + n)*H_ + t*4);
    acc.x += al*bf2f(x.x); acc.y += al*bf2f(x.y);
    acc.z += al*bf2f(x.z); acc.w += al*bf2f(x.w);
  }
  *(float4*)(outCtx + (size_t)b*H_ + t*4) = acc;
}

// ---------- fallback score GEMM (round-1) ----------
__global__ __launch_bounds__(256) void k_scores_f(
    const float* __restrict__ img, const unsigned short* __restrict__ WtImg,
    const float* __restrict__ hproj, const float* __restrict__ b_img,
    const float* __restrict__ cov, const float* __restrict__ Wcov,
    const float* __restrict__ v, float* __restrict__ scores){
  __shared__ __align__(16) unsigned short sA[128][LDK];
  __shared__ __align__(16) unsigned short sB[128][LDK];
  __shared__ float sH[4][128];
  f32x4 acc[4][4];
  int m0 = blockIdx.x * 128, a0 = blockIdx.y * 128;
  gemm_tile(img, WtImg, m0, a0, acc, sA, sB);
  int bFirst = m0 / N_;
  int bLast  = (m0 + 127) / N_;
  int nB = bLast - bFirst + 1;
  for (int idx = threadIdx.x; idx < nB*128; idx += 256){
    int bb = idx >> 7, a = idx & 127;
    sH[bb][a] = hproj[(size_t)(bFirst + bb)*A_ + a0 + a];
  }
  __syncthreads();
  const int l = threadIdx.x & 63, w = threadIdx.x >> 6;
  const int wr = w >> 1, wc = w & 1, g = l >> 4, c = l & 15;
  float vv[4], bi[4], wcv[4];
  #pragma unroll
  for (int n=0;n<4;n++){
    int col = a0 + wc*64 + n*16 + c;
    vv[n] = v[col]; bi[n] = b_img[col]; wcv[n] = Wcov[col];
  }
  #pragma unroll
  for (int m=0;m<4;m++)
    #pragma unroll
    for (int r=0;r<4;r++){
      int rowg = m0 + wr*64 + m*16 + g*4 + r;
      int bb = rowg / N_;
      float cv = cov[rowg];
      float s = 0.f;
      #pragma unroll
      for (int n=0;n<4;n++){
        float x = acc[m][n][r] + sH[bb - bFirst][wc*64 + n*16 + c] + bi[n] + cv*wcv[n];
        s += fast_tanh(x) * vv[n];
      }
      s += __shfl_xor(s, 1, 16);
      s += __shfl_xor(s, 2, 16);
      s += __shfl_xor(s, 4, 16);
      s += __shfl_xor(s, 8, 16);
      if (c == 0) atomicAdd(&scores[rowg], s);
    }
}

// ---------- fallback softmax + context ----------
__global__ __launch_bounds__(256) void k_ctx_f(
    const float* __restrict__ img, const float* __restrict__ scores,
    float* __restrict__ outCtx, float* __restrict__ outAlpha){
  int b = blockIdx.x;
  __shared__ float sAl[N_];
  int t = threadIdx.x;
  if (t < 64){
    float s = (t < N_) ? scores[(size_t)b*N_ + t] : -1e30f;
    float m = s;
    #pragma unroll
    for (int off=32; off>=1; off>>=1) m = fmaxf(m, __shfl_xor(m, off));
    float e = (t < N_) ? __expf(s - m) : 0.f;
    float sum = e;
    #pragma unroll
    for (int off=32; off>=1; off>>=1) sum += __shfl_xor(sum, off);
    float al = e / sum;
    if (t < N_){ sAl[t] = al; outAlpha[(size_t)b*N_ + t] = al; }
  }
  __syncthreads();
  const float4* ib = (const float4*)(img + (size_t)b*N_*H_);
  float4 acc = {0.f,0.f,0.f,0.f};
  for (int n=0;n<N_;n++){
    float al = sAl[n];
    float4 x = ib[n*(H_/4) + t];
    acc.x += al*x.x; acc.y += al*x.y; acc.z += al*x.z; acc.w += al*x.w;
  }
  *(float4*)(outCtx + (size_t)b*H_ + t*4) = acc;
}

extern "C" void kernel_launch(void* const* d_in, const int* in_sizes, int n_in,
                              void* d_out, int out_size, void* d_ws, size_t ws_size,
                              hipStream_t stream){
  const float* hidden = (const float*)d_in[0];
  const float* img    = (const float*)d_in[1];
  const float* cov    = (const float*)d_in[2];
  const float* W_h    = (const float*)d_in[3];
  const float* b_h    = (const float*)d_in[4];
  const float* W_img  = (const float*)d_in[5];
  const float* b_img  = (const float*)d_in[6];
  const float* W_cov  = (const float*)d_in[7];
  const float* v      = (const float*)d_in[8];

  char* ws = (char*)d_ws;
  unsigned short* WtH   = (unsigned short*)ws;               // 1 MB
  unsigned short* WtImg = (unsigned short*)(ws + (1u<<20));  // 1 MB
  float* hproj   = (float*)(ws + (2u<<20));                  // 4 MB
  float* scoresP = (float*)(ws + (6u<<20));                  // 2 slabs, 0.8 MB
  unsigned short* imgb = (unsigned short*)(ws + (8u<<20));   // 196 MB bf16 copy

  float* outCtx   = (float*)d_out;
  float* outAlpha = outCtx + (size_t)B_*H_;

  const size_t needed = (8ull<<20) + (size_t)M_*H_*2;

  k_transpose<<<dim3(512, 2), 256, 0, stream>>>(W_h, W_img, WtH, WtImg);
  k_hproj<<<dim3(B_/128, A_/128), 256, 0, stream>>>(hidden, WtH, b_h, hproj);

  if (ws_size >= needed){
    k_convert<<<2048, 256, 0, stream>>>(img, imgb, (size_t)M_*H_/8);
    k_scores_q<<<(M_/256)*(A_/256), 512, 0, stream>>>(imgb, WtImg, hproj, b_img, cov, W_cov, v, scoresP);
    k_ctx_b<<<B_, 256, 0, stream>>>(imgb, scoresP, outCtx, outAlpha);
  } else {
    hipMemsetAsync(scoresP, 0, (size_t)M_*sizeof(float), stream);
    k_scores_f<<<dim3(M_/128, A_/128), 256, 0, stream>>>(img, WtImg, hproj, b_img, cov, W_cov, v, scoresP);
    k_ctx_f<<<B_, 256, 0, stream>>>(img, scoresP, outCtx, outAlpha);
  }
}

// Round 15
// 346.455 us; speedup vs baseline: 3.1487x; 3.1487x over previous
//
#include <hip/hip_runtime.h>
#include <cstdint>
#include <cstddef>

#define B_ 2048
#define N_ 49
#define H_ 1024
#define A_ 512
#define M_ (B_*N_)   // 100352 = 392*256

typedef __attribute__((ext_vector_type(8))) short short8;
typedef __attribute__((ext_vector_type(8))) unsigned short ushort8;
typedef __attribute__((ext_vector_type(4))) float f32x4;
typedef unsigned int u32;

__device__ inline unsigned short f2bf(float f){
  union { float f; unsigned u; } v; v.f = f;
  unsigned r = v.u + 0x7FFFu + ((v.u >> 16) & 1u);   // RNE
  return (unsigned short)(r >> 16);
}
__device__ inline float bf2f(unsigned short h){
  union { u32 u; float f; } v; v.u = ((u32)h) << 16; return v.f;
}
__device__ inline float fast_tanh(float x){
  float e = __expf(2.0f*x);
  return 1.0f - 2.0f/(e + 1.0f);
}
__device__ inline void gl16(const void* g, void* l){
  __builtin_amdgcn_global_load_lds((const __attribute__((address_space(1))) u32*)g,
                                   (__attribute__((address_space(3))) u32*)l, 16, 0, 0);
}

// ---------- W (H x A fp32, row-major) -> Wt (A x H bf16) ----------
__global__ __launch_bounds__(256) void k_transpose(
    const float* __restrict__ Wh, const float* __restrict__ Wimg,
    unsigned short* __restrict__ WtH, unsigned short* __restrict__ WtImg){
  const float* src = blockIdx.y ? Wimg : Wh;
  unsigned short* dst = blockIdx.y ? WtImg : WtH;
  int tk = (blockIdx.x & 31) * 32;
  int ta = (blockIdx.x >> 5) * 32;
  __shared__ unsigned short tile[32][33];
  int t = threadIdx.x;
  int r = t >> 3, c4 = t & 7;
  float4 vv = *(const float4*)(src + (size_t)(tk + r)*A_ + ta + c4*4);
  tile[c4*4+0][r] = f2bf(vv.x);
  tile[c4*4+1][r] = f2bf(vv.y);
  tile[c4*4+2][r] = f2bf(vv.z);
  tile[c4*4+3][r] = f2bf(vv.w);
  __syncthreads();
  ushort4 o;
  o.x = tile[r][c4*4+0]; o.y = tile[r][c4*4+1];
  o.z = tile[r][c4*4+2]; o.w = tile[r][c4*4+3];
  *(ushort4*)(dst + (size_t)(ta + r)*H_ + tk + c4*4) = o;
}

// ---------- img fp32 -> bf16 ----------
__global__ __launch_bounds__(256) void k_convert(
    const float* __restrict__ src, unsigned short* __restrict__ dst, size_t n8){
  size_t i = (size_t)blockIdx.x*256 + threadIdx.x;
  size_t stride = (size_t)gridDim.x*256;
  const float4* s4 = (const float4*)src;
  ushort8* d8 = (ushort8*)dst;
  for (; i < n8; i += stride){
    float4 a = s4[2*i], b = s4[2*i+1];
    ushort8 o;
    o[0]=f2bf(a.x); o[1]=f2bf(a.y); o[2]=f2bf(a.z); o[3]=f2bf(a.w);
    o[4]=f2bf(b.x); o[5]=f2bf(b.y); o[6]=f2bf(b.z); o[7]=f2bf(b.w);
    d8[i] = o;
  }
}

// ================= fallback GEMM core (round-1) =================
#define BK 64
#define LDK 72

__device__ inline void gemm_tile(const float* __restrict__ Asrc,
                                 const unsigned short* __restrict__ Wt,
                                 int m0, int a0, f32x4 acc[4][4],
                                 unsigned short (*sA)[LDK], unsigned short (*sB)[LDK]){
  const int t = threadIdx.x;
  const int l = t & 63, w = t >> 6;
  const int wr = w >> 1, wc = w & 1;
  const int g = l >> 4, c = l & 15;
  #pragma unroll
  for (int m=0;m<4;m++)
    #pragma unroll
    for (int n=0;n<4;n++)
      acc[m][n] = f32x4{0.f,0.f,0.f,0.f};

  for (int k0 = 0; k0 < H_; k0 += BK){
    #pragma unroll
    for (int i=0;i<8;i++){
      int f = i*256 + t;
      int row = f >> 4, c4 = f & 15;
      float4 vv = *(const float4*)(Asrc + (size_t)(m0+row)*H_ + k0 + c4*4);
      ushort4 h; h.x=f2bf(vv.x); h.y=f2bf(vv.y); h.z=f2bf(vv.z); h.w=f2bf(vv.w);
      *(ushort4*)&sA[row][c4*4] = h;
    }
    #pragma unroll
    for (int i=0;i<8;i++){
      int f = i*256 + t;
      int row = f >> 4, c4 = f & 15;
      *(ushort4*)&sB[row][c4*4] = *(const ushort4*)(Wt + (size_t)(a0+row)*H_ + k0 + c4*4);
    }
    __syncthreads();
    #pragma unroll
    for (int kk=0; kk<BK; kk+=32){
      short8 aF[4], bF[4];
      #pragma unroll
      for (int m=0;m<4;m++) aF[m] = *(const short8*)&sA[wr*64 + m*16 + c][kk + g*8];
      #pragma unroll
      for (int n=0;n<4;n++) bF[n] = *(const short8*)&sB[wc*64 + n*16 + c][kk + g*8];
      #pragma unroll
      for (int m=0;m<4;m++)
        #pragma unroll
        for (int n=0;n<4;n++)
          acc[m][n] = __builtin_amdgcn_mfma_f32_16x16x32_bf16(aF[m], bF[n], acc[m][n], 0, 0, 0);
    }
    __syncthreads();
  }
}

// ---------- h_proj = hidden @ W_h + b_h ----------
__global__ __launch_bounds__(256) void k_hproj(
    const float* __restrict__ hidden, const unsigned short* __restrict__ WtH,
    const float* __restrict__ b_h, float* __restrict__ hproj){
  __shared__ __align__(16) unsigned short sA[128][LDK];
  __shared__ __align__(16) unsigned short sB[128][LDK];
  f32x4 acc[4][4];
  int m0 = blockIdx.x * 128, a0 = blockIdx.y * 128;
  gemm_tile(hidden, WtH, m0, a0, acc, sA, sB);
  const int l = threadIdx.x & 63, w = threadIdx.x >> 6;
  const int wr = w >> 1, wc = w & 1, g = l >> 4, c = l & 15;
  #pragma unroll
  for (int n=0;n<4;n++){
    int col = a0 + wc*64 + n*16 + c;
    float bh = b_h[col];
    #pragma unroll
    for (int m=0;m<4;m++)
      #pragma unroll
      for (int r=0;r<4;r++){
        int rowg = m0 + wr*64 + m*16 + g*4 + r;
        hproj[(size_t)rowg*A_ + col] = acc[m][n][r] + bh;
      }
  }
}

// ============ scores GEMM: 256x256/BK=64, 8-phase interleave (T3+T4) ============
// Staging split into 64-row QUARTER units (1 gl16/thread each), stream order per tile
// [B00,B01,B10,B11,A0lo,A1lo,A0hi,A1hi]; issues distributed 2/phase; counted vmcnt at
// P0 (vmcnt(4): units 1-6 of tile t landed) and P2 (vmcnt(6): A-hi landed) -- never 0
// in the main loop. Phase = {issue 2 units; [wait]; barrier; ds_read 8xb128;
// lgkmcnt(0)+sched_barrier; setprio 16xMFMA; barrier}.
__global__ __launch_bounds__(512, 2) void k_scores_p8(
    const unsigned short* __restrict__ Ab, const unsigned short* __restrict__ Wt,
    const float* __restrict__ hproj, const float* __restrict__ b_img,
    const float* __restrict__ cov, const float* __restrict__ Wcov,
    const float* __restrict__ v, float* __restrict__ scoresP){
  __shared__ __align__(16) char lds[131072];
  const int t = threadIdx.x;
  const int l = t & 63, w = t >> 6;       // 8 waves
  const int wr = w >> 2, wc = w & 3;      // 2 (M) x 4 (N)
  const int g = l >> 4, c = l & 15;
  const int cm = (c & 7) << 4;            // read-side XOR swizzle

  // bijective XCD-chunked swizzle; wg pairs (same m-panel, a0=0/256) adjacent on one XCD.
  const int nwg = (M_/256)*(A_/256);      // 784, %8==0
  int bid = blockIdx.x;
  int wg = (bid & 7)*(nwg/8) + (bid >> 3);
  const int m0 = (wg >> 1) * 256;
  const int a0 = (wg & 1) * 256;

  const int rsub = l >> 3;
  const int ksw  = ((l & 7) ^ rsub) * 8;  // pre-swizzled global k-offset (elements)

  f32x4 acc[8][4] = {};

  // one 64-row quarter: 1 gl16/thread. LDS row == panel row (within half); slot s=l&7
  // holds global k-granule s^(row&7) (row&7 == rsub since row0, w*8 are 0 mod 8).
  auto unit = [&](int d, int opoff, int h, int row0,
                  const unsigned short* src, int prow, int k0){
    gl16(src + (size_t)(prow + h*128 + row0 + w*8 + rsub)*H_ + k0 + ksw,
         lds + d*65536 + opoff + h*16384 + row0*128 + w*1024);
  };

  const int abase_s = wr*16384;                // wave's A half
  const int bbase_s = 32768 + (wc>>1)*16384;   // wave's B half
  const int brow    = (wc & 1)*64;

  // quadrant (mh, kb): 8 ds_read_b128 + 16 MFMA
  auto phase_mfma = [&](int cur, int mh, int kb){
    short8 aF[4], bF[4];
    #pragma unroll
    for (int i=0;i<4;i++)
      aF[i] = *(const short8*)(lds + cur + abase_s + (mh*64 + i*16 + c)*128 + ((kb*64 + g*16) ^ cm));
    #pragma unroll
    for (int n=0;n<4;n++)
      bF[n] = *(const short8*)(lds + cur + bbase_s + (brow + n*16 + c)*128 + ((kb*64 + g*16) ^ cm));
    asm volatile("s_waitcnt lgkmcnt(0)" ::: "memory");
    __builtin_amdgcn_sched_barrier(0);
    __builtin_amdgcn_s_setprio(1);
    #pragma unroll
    for (int i=0;i<4;i++)
      #pragma unroll
      for (int n=0;n<4;n++)
        acc[mh*4+i][n] = __builtin_amdgcn_mfma_f32_16x16x32_bf16(aF[i], bF[n], acc[mh*4+i][n], 0, 0, 0);
    __builtin_amdgcn_s_setprio(0);
  };

  // prologue: tile 0, all 8 units in stream order
  unit(0, 32768, 0, 0,  Wt, a0, 0);
  unit(0, 32768, 0, 64, Wt, a0, 0);
  unit(0, 32768, 1, 0,  Wt, a0, 0);
  unit(0, 32768, 1, 64, Wt, a0, 0);
  unit(0, 0,     0, 0,  Ab, m0, 0);
  unit(0, 0,     1, 0,  Ab, m0, 0);
  unit(0, 0,     0, 64, Ab, m0, 0);
  unit(0, 0,     1, 64, Ab, m0, 0);

  for (int tt=0; tt<16; ++tt){
    const int cur = (tt & 1) << 16;
    const int nd  = (tt + 1) & 1;
    const int nk  = (tt + 1) * 64;
    const bool pf = (tt < 15);

    // ---- P0: (mh0, kb0); prefetch B-h0 lo/hi.
    // ledger after issue: [t:A0hi,A1hi | t':B00,B01] -> vmcnt(4) = units 1-6 of t landed.
    if (pf){ unit(nd, 32768, 0, 0, Wt, a0, nk); unit(nd, 32768, 0, 64, Wt, a0, nk);
             asm volatile("s_waitcnt vmcnt(4)" ::: "memory"); }
    else   { asm volatile("s_waitcnt vmcnt(2)" ::: "memory"); }
    asm volatile("s_barrier" ::: "memory");
    phase_mfma(cur, 0, 0);
    asm volatile("s_barrier" ::: "memory");

    // ---- P1: (mh0, kb1); prefetch B-h1 lo/hi (no wait needed)
    if (pf){ unit(nd, 32768, 1, 0, Wt, a0, nk); unit(nd, 32768, 1, 64, Wt, a0, nk); }
    asm volatile("s_barrier" ::: "memory");
    phase_mfma(cur, 0, 1);
    asm volatile("s_barrier" ::: "memory");

    // ---- P2: (mh1, kb0); prefetch A lo (h0,h1).
    // ledger after issue: [t:A0hi,A1hi | t':B x4, Alo x2] = 8 -> vmcnt(6) retires t's A-hi.
    if (pf){ unit(nd, 0, 0, 0, Ab, m0, nk); unit(nd, 0, 1, 0, Ab, m0, nk);
             asm volatile("s_waitcnt vmcnt(6)" ::: "memory"); }
    else   { asm volatile("s_waitcnt vmcnt(0)" ::: "memory"); }
    asm volatile("s_barrier" ::: "memory");
    phase_mfma(cur, 1, 0);
    asm volatile("s_barrier" ::: "memory");

    // ---- P3: (mh1, kb1); prefetch A hi (h0,h1) (no wait needed)
    if (pf){ unit(nd, 0, 0, 64, Ab, m0, nk); unit(nd, 0, 1, 64, Ab, m0, nk); }
    asm volatile("s_barrier" ::: "memory");
    phase_mfma(cur, 1, 1);
    asm volatile("s_barrier" ::: "memory");
  }

  // ---------------- epilogue: tanh + v-dot + row-reduce ----------------
  float* sS = (float*)lds;            // [256]
  float* sH = (float*)lds + 256;      // [nB][256], nB<=7
  const int bFirst = m0 / N_;
  const int nB = (m0 + 255)/N_ - bFirst + 1;
  if (t < 256) sS[t] = 0.f;
  for (int idx = t; idx < nB*256; idx += 512){
    int bb = idx >> 8, a = idx & 255;
    sH[bb*256 + a] = hproj[(size_t)(bFirst + bb)*A_ + a0 + a];
  }
  __syncthreads();

  float vv[4], bi[4], wcv[4];
  #pragma unroll
  for (int n=0;n<4;n++){
    int colg = a0 + wc*64 + n*16 + c;
    vv[n] = v[colg]; bi[n] = b_img[colg]; wcv[n] = Wcov[colg];
  }
  #pragma unroll
  for (int m=0;m<8;m++){
    #pragma unroll
    for (int r=0;r<4;r++){
      int rowl = wr*128 + m*16 + g*4 + r;
      int bb = (m0 + rowl) / N_ - bFirst;
      float cv = cov[m0 + rowl];
      float s = 0.f;
      #pragma unroll
      for (int n=0;n<4;n++){
        float x = acc[m][n][r] + sH[bb*256 + wc*64 + n*16 + c] + bi[n] + cv*wcv[n];
        s += fast_tanh(x) * vv[n];
      }
      s += __shfl_xor(s, 1, 16);
      s += __shfl_xor(s, 2, 16);
      s += __shfl_xor(s, 4, 16);
      s += __shfl_xor(s, 8, 16);
      if (c == 0) atomicAdd(&sS[rowl], s);
    }
  }
  __syncthreads();
  if (t < 256) scoresP[(size_t)(a0 >> 8)*M_ + m0 + t] = sS[t];
}

// ---------- softmax (2-slab scores) + context from bf16 imgb ----------
__global__ __launch_bounds__(256) void k_ctx_b(
    const unsigned short* __restrict__ imgb, const float* __restrict__ scoresP,
    float* __restrict__ outCtx, float* __restrict__ outAlpha){
  int b = blockIdx.x;
  __shared__ float sAl[N_];
  int t = threadIdx.x;
  if (t < 64){
    float s = -1e30f;
    if (t < N_){
      size_t rg = (size_t)b*N_ + t;
      s = scoresP[rg] + scoresP[(size_t)M_ + rg];
    }
    float m = s;
    #pragma unroll
    for (int off=32; off>=1; off>>=1) m = fmaxf(m, __shfl_xor(m, off));
    float e = (t < N_) ? __expf(s - m) : 0.f;
    float sum = e;
    #pragma unroll
    for (int off=32; off>=1; off>>=1) sum += __shfl_xor(sum, off);
    float al = e / sum;
    if (t < N_){ sAl[t] = al; outAlpha[(size_t)b*N_ + t] = al; }
  }
  __syncthreads();
  float4 acc = {0.f,0.f,0.f,0.f};
  #pragma unroll 7
  for (int n=0;n<N_;n++){
    float al = sAl[n];
    ushort4 x = *(const ushort4*)(imgb + ((size_t)b*N_ + n)*H_ + t*4);
    acc.x += al*bf2f(x.x); acc.y += al*bf2f(x.y);
    acc.z += al*bf2f(x.z); acc.w += al*bf2f(x.w);
  }
  *(float4*)(outCtx + (size_t)b*H_ + t*4) = acc;
}

// ---------- fallback score GEMM (round-1) ----------
__global__ __launch_bounds__(256) void k_scores_f(
    const float* __restrict__ img, const unsigned short* __restrict__ WtImg,
    const float* __restrict__ hproj, const float* __restrict__ b_img,
    const float* __restrict__ cov, const float* __restrict__ Wcov,
    const float* __restrict__ v, float* __restrict__ scores){
  __shared__ __align__(16) unsigned short sA[128][LDK];
  __shared__ __align__(16) unsigned short sB[128][LDK];
  __shared__ float sH[4][128];
  f32x4 acc[4][4];
  int m0 = blockIdx.x * 128, a0 = blockIdx.y * 128;
  gemm_tile(img, WtImg, m0, a0, acc, sA, sB);
  int bFirst = m0 / N_;
  int bLast  = (m0 + 127) / N_;
  int nB = bLast - bFirst + 1;
  for (int idx = threadIdx.x; idx < nB*128; idx += 256){
    int bb = idx >> 7, a = idx & 127;
    sH[bb][a] = hproj[(size_t)(bFirst + bb)*A_ + a0 + a];
  }
  __syncthreads();
  const int l = threadIdx.x & 63, w = threadIdx.x >> 6;
  const int wr = w >> 1, wc = w & 1, g = l >> 4, c = l & 15;
  float vv[4], bi[4], wcv[4];
  #pragma unroll
  for (int n=0;n<4;n++){
    int col = a0 + wc*64 + n*16 + c;
    vv[n] = v[col]; bi[n] = b_img[col]; wcv[n] = Wcov[col];
  }
  #pragma unroll
  for (int m=0;m<4;m++)
    #pragma unroll
    for (int r=0;r<4;r++){
      int rowg = m0 + wr*64 + m*16 + g*4 + r;
      int bb = rowg / N_;
      float cv = cov[rowg];
      float s = 0.f;
      #pragma unroll
      for (int n=0;n<4;n++){
        float x = acc[m][n][r] + sH[bb - bFirst][wc*64 + n*16 + c] + bi[n] + cv*wcv[n];
        s += fast_tanh(x) * vv[n];
      }
      s += __shfl_xor(s, 1, 16);
      s += __shfl_xor(s, 2, 16);
      s += __shfl_xor(s, 4, 16);
      s += __shfl_xor(s, 8, 16);
      if (c == 0) atomicAdd(&scores[rowg], s);
    }
}

// ---------- fallback softmax + context ----------
__global__ __launch_bounds__(256) void k_ctx_f(
    const float* __restrict__ img, const float* __restrict__ scores,
    float* __restrict__ outCtx, float* __restrict__ outAlpha){
  int b = blockIdx.x;
  __shared__ float sAl[N_];
  int t = threadIdx.x;
  if (t < 64){
    float s = (t < N_) ? scores[(size_t)b*N_ + t] : -1e30f;
    float m = s;
    #pragma unroll
    for (int off=32; off>=1; off>>=1) m = fmaxf(m, __shfl_xor(m, off));
    float e = (t < N_) ? __expf(s - m) : 0.f;
    float sum = e;
    #pragma unroll
    for (int off=32; off>=1; off>>=1) sum += __shfl_xor(sum, off);
    float al = e / sum;
    if (t < N_){ sAl[t] = al; outAlpha[(size_t)b*N_ + t] = al; }
  }
  __syncthreads();
  const float4* ib = (const float4*)(img + (size_t)b*N_*H_);
  float4 acc = {0.f,0.f,0.f,0.f};
  for (int n=0;n<N_;n++){
    float al = sAl[n];
    float4 x = ib[n*(H_/4) + t];
    acc.x += al*x.x; acc.y += al*x.y; acc.z += al*x.z; acc.w += al*x.w;
  }
  *(float4*)(outCtx + (size_t)b*H_ + t*4) = acc;
}

extern "C" void kernel_launch(void* const* d_in, const int* in_sizes, int n_in,
                              void* d_out, int out_size, void* d_ws, size_t ws_size,
                              hipStream_t stream){
  const float* hidden = (const float*)d_in[0];
  const float* img    = (const float*)d_in[1];
  const float* cov    = (const float*)d_in[2];
  const float* W_h    = (const float*)d_in[3];
  const float* b_h    = (const float*)d_in[4];
  const float* W_img  = (const float*)d_in[5];
  const float* b_img  = (const float*)d_in[6];
  const float* W_cov  = (const float*)d_in[7];
  const float* v      = (const float*)d_in[8];

  char* ws = (char*)d_ws;
  unsigned short* WtH   = (unsigned short*)ws;               // 1 MB
  unsigned short* WtImg = (unsigned short*)(ws + (1u<<20));  // 1 MB
  float* hproj   = (float*)(ws + (2u<<20));                  // 4 MB
  float* scoresP = (float*)(ws + (6u<<20));                  // 2 slabs, 0.8 MB
  unsigned short* imgb = (unsigned short*)(ws + (8u<<20));   // 196 MB bf16 copy

  float* outCtx   = (float*)d_out;
  float* outAlpha = outCtx + (size_t)B_*H_;

  const size_t needed = (8ull<<20) + (size_t)M_*H_*2;

  k_transpose<<<dim3(512, 2), 256, 0, stream>>>(W_h, W_img, WtH, WtImg);
  k_hproj<<<dim3(B_/128, A_/128), 256, 0, stream>>>(hidden, WtH, b_h, hproj);

  if (ws_size >= needed){
    k_convert<<<2048, 256, 0, stream>>>(img, imgb, (size_t)M_*H_/8);
    k_scores_p8<<<(M_/256)*(A_/256), 512, 0, stream>>>(imgb, WtImg, hproj, b_img, cov, W_cov, v, scoresP);
    k_ctx_b<<<B_, 256, 0, stream>>>(imgb, scoresP, outCtx, outAlpha);
  } else {
    hipMemsetAsync(scoresP, 0, (size_t)M_*sizeof(float), stream);
    k_scores_f<<<dim3(M_/128, A_/128), 256, 0, stream>>>(img, WtImg, hproj, b_img, cov, W_cov, v, scoresP);
    k_ctx_f<<<B_, 256, 0, stream>>>(img, scoresP, outCtx, outAlpha);
  }
}